// Round 1
// baseline (16448.070 us; speedup 1.0000x reference)
//
#include <hip/hip_runtime.h>

#define N_NODES 500000
#define N_EDGES 5000000
#define N_GRAPHS 5000
#define FEAT 7
#define STATE 16

// ---------------- input layer: state = relu(x @ in_W + in_b) ----------------
__global__ __launch_bounds__(256) void k_input(const float* __restrict__ x,
                                               const float* __restrict__ W,
                                               const float* __restrict__ b,
                                               float* __restrict__ state) {
    int i = blockIdx.x * 256 + threadIdx.x;
    if (i >= N_NODES) return;
    float xi[FEAT];
#pragma unroll
    for (int f = 0; f < FEAT; ++f) xi[f] = x[(size_t)i * FEAT + f];
    float o[STATE];
#pragma unroll
    for (int s = 0; s < STATE; ++s) {
        float acc = b[s];
#pragma unroll
        for (int f = 0; f < FEAT; ++f) acc = fmaf(xi[f], W[f * STATE + s], acc);
        o[s] = fmaxf(acc, 0.f);
    }
    float4* dst = reinterpret_cast<float4*>(state + (size_t)i * STATE);
#pragma unroll
    for (int q = 0; q < 4; ++q)
        dst[q] = make_float4(o[4 * q], o[4 * q + 1], o[4 * q + 2], o[4 * q + 3]);
}

// ------- message = relu(state @ W + b); also zero agg for this round --------
__global__ __launch_bounds__(256) void k_message(const float* __restrict__ state,
                                                 const float* __restrict__ W,
                                                 const float* __restrict__ b,
                                                 float* __restrict__ message,
                                                 float* __restrict__ agg) {
    int i = blockIdx.x * 256 + threadIdx.x;
    if (i >= N_NODES) return;
    const float4* sp = reinterpret_cast<const float4*>(state + (size_t)i * STATE);
    float4 v0 = sp[0], v1 = sp[1], v2 = sp[2], v3 = sp[3];
    float st[STATE] = {v0.x, v0.y, v0.z, v0.w, v1.x, v1.y, v1.z, v1.w,
                       v2.x, v2.y, v2.z, v2.w, v3.x, v3.y, v3.z, v3.w};
    float o[STATE];
#pragma unroll
    for (int s = 0; s < STATE; ++s) {
        float acc = b[s];
#pragma unroll
        for (int k = 0; k < STATE; ++k) acc = fmaf(st[k], W[k * STATE + s], acc);
        o[s] = fmaxf(acc, 0.f);
    }
    float4* mp = reinterpret_cast<float4*>(message + (size_t)i * STATE);
#pragma unroll
    for (int q = 0; q < 4; ++q)
        mp[q] = make_float4(o[4 * q], o[4 * q + 1], o[4 * q + 2], o[4 * q + 3]);
    float4 z = make_float4(0.f, 0.f, 0.f, 0.f);
    float4* ap = reinterpret_cast<float4*>(agg + (size_t)i * STATE);
#pragma unroll
    for (int q = 0; q < 4; ++q) ap[q] = z;
}

// ------------- edge scatter: agg[dst[e]] += message[src[e]] -----------------
__global__ __launch_bounds__(256) void k_edge(const int* __restrict__ ei,
                                              const float* __restrict__ message,
                                              float* __restrict__ agg) {
    int e = blockIdx.x * 256 + threadIdx.x;
    if (e >= N_EDGES) return;
    int s = ei[e];
    int d = ei[N_EDGES + e];
    const float4* mp = reinterpret_cast<const float4*>(message + (size_t)s * STATE);
    float4 m0 = mp[0], m1 = mp[1], m2 = mp[2], m3 = mp[3];
    float* ap = agg + (size_t)d * STATE;
    unsafeAtomicAdd(ap + 0, m0.x);  unsafeAtomicAdd(ap + 1, m0.y);
    unsafeAtomicAdd(ap + 2, m0.z);  unsafeAtomicAdd(ap + 3, m0.w);
    unsafeAtomicAdd(ap + 4, m1.x);  unsafeAtomicAdd(ap + 5, m1.y);
    unsafeAtomicAdd(ap + 6, m1.z);  unsafeAtomicAdd(ap + 7, m1.w);
    unsafeAtomicAdd(ap + 8, m2.x);  unsafeAtomicAdd(ap + 9, m2.y);
    unsafeAtomicAdd(ap + 10, m2.z); unsafeAtomicAdd(ap + 11, m2.w);
    unsafeAtomicAdd(ap + 12, m3.x); unsafeAtomicAdd(ap + 13, m3.y);
    unsafeAtomicAdd(ap + 14, m3.z); unsafeAtomicAdd(ap + 15, m3.w);
}

// ------------- state += relu(agg @ W + b) -----------------------------------
__global__ __launch_bounds__(256) void k_update(const float* __restrict__ agg,
                                                const float* __restrict__ W,
                                                const float* __restrict__ b,
                                                float* __restrict__ state) {
    int i = blockIdx.x * 256 + threadIdx.x;
    if (i >= N_NODES) return;
    const float4* apv = reinterpret_cast<const float4*>(agg + (size_t)i * STATE);
    float4 v0 = apv[0], v1 = apv[1], v2 = apv[2], v3 = apv[3];
    float ag[STATE] = {v0.x, v0.y, v0.z, v0.w, v1.x, v1.y, v1.z, v1.w,
                       v2.x, v2.y, v2.z, v2.w, v3.x, v3.y, v3.z, v3.w};
    float* sp = state + (size_t)i * STATE;
    float4* spv = reinterpret_cast<float4*>(sp);
    float4 s0 = spv[0], s1 = spv[1], s2 = spv[2], s3 = spv[3];
    float st[STATE] = {s0.x, s0.y, s0.z, s0.w, s1.x, s1.y, s1.z, s1.w,
                       s2.x, s2.y, s2.z, s2.w, s3.x, s3.y, s3.z, s3.w};
#pragma unroll
    for (int s = 0; s < STATE; ++s) {
        float acc = b[s];
#pragma unroll
        for (int k = 0; k < STATE; ++k) acc = fmaf(ag[k], W[k * STATE + s], acc);
        st[s] += fmaxf(acc, 0.f);
    }
#pragma unroll
    for (int q = 0; q < 4; ++q)
        spv[q] = make_float4(st[4 * q], st[4 * q + 1], st[4 * q + 2], st[4 * q + 3]);
}

// ------------- out[g] = out_b -----------------------------------------------
__global__ __launch_bounds__(256) void k_out_init(const float* __restrict__ out_b,
                                                  float* __restrict__ out) {
    int g = blockIdx.x * 256 + threadIdx.x;
    if (g < N_GRAPHS) out[g] = out_b[0];
}

// ------------- out[batch[i]] += dot(state[i], out_W) ------------------------
// batch is sorted -> wave-segmented reduction, ~1-2 atomics per wave.
__global__ __launch_bounds__(256) void k_reduce(const float* __restrict__ state,
                                                const int* __restrict__ batch,
                                                const float* __restrict__ out_W,
                                                float* __restrict__ out) {
    int i = blockIdx.x * 256 + threadIdx.x;
    int lane = threadIdx.x & 63;
    bool valid = (i < N_NODES);
    float v = 0.f;
    int bg = -1;
    if (valid) {
        bg = batch[i];
        const float4* sp = reinterpret_cast<const float4*>(state + (size_t)i * STATE);
        float4 s0 = sp[0], s1 = sp[1], s2 = sp[2], s3 = sp[3];
        float st[STATE] = {s0.x, s0.y, s0.z, s0.w, s1.x, s1.y, s1.z, s1.w,
                           s2.x, s2.y, s2.z, s2.w, s3.x, s3.y, s3.z, s3.w};
        float acc = 0.f;
#pragma unroll
        for (int k = 0; k < STATE; ++k) acc = fmaf(st[k], out_W[k], acc);
        v = acc;
    }
    // segmented inclusive scan over sorted keys within the wave
#pragma unroll
    for (int off = 1; off < 64; off <<= 1) {
        float ov = __shfl_up(v, off);
        int ob = __shfl_up(bg, off);
        if (lane >= off && ob == bg) v += ov;
    }
    int nb = __shfl_down(bg, 1);
    if (valid && (lane == 63 || nb != bg)) unsafeAtomicAdd(&out[bg], v);
}

extern "C" void kernel_launch(void* const* d_in, const int* in_sizes, int n_in,
                              void* d_out, int out_size, void* d_ws, size_t ws_size,
                              hipStream_t stream) {
    const float* x     = (const float*)d_in[0];
    const int*   ei    = (const int*)d_in[1];
    const int*   batch = (const int*)d_in[2];
    const float* in_W  = (const float*)d_in[3];
    const float* in_b  = (const float*)d_in[4];
    const float* msg_W = (const float*)d_in[5];
    const float* msg_b = (const float*)d_in[6];
    const float* upd_W = (const float*)d_in[7];
    const float* upd_b = (const float*)d_in[8];
    const float* out_W = (const float*)d_in[9];
    const float* out_b = (const float*)d_in[10];
    float* out = (float*)d_out;

    float* state   = (float*)d_ws;                       // 32 MB
    float* message = state + (size_t)N_NODES * STATE;    // 32 MB
    float* agg     = message + (size_t)N_NODES * STATE;  // 32 MB

    const int nbN = (N_NODES + 255) / 256;
    const int nbE = (N_EDGES + 255) / 256;
    const int nbG = (N_GRAPHS + 255) / 256;

    k_input<<<nbN, 256, 0, stream>>>(x, in_W, in_b, state);
    for (int r = 0; r < 4; ++r) {
        k_message<<<nbN, 256, 0, stream>>>(state, msg_W + r * STATE * STATE,
                                           msg_b + r * STATE, message, agg);
        k_edge<<<nbE, 256, 0, stream>>>(ei, message, agg);
        k_update<<<nbN, 256, 0, stream>>>(agg, upd_W + r * STATE * STATE,
                                          upd_b + r * STATE, state);
    }
    k_out_init<<<nbG, 256, 0, stream>>>(out_b, out);
    k_reduce<<<nbN, 256, 0, stream>>>(state, batch, out_W, out);
}

// Round 3
// 971.783 us; speedup vs baseline: 16.9257x; 16.9257x over previous
//
#include <hip/hip_runtime.h>

#define N_NODES 500000
#define N_EDGES 5000000
#define N_GRAPHS 5000
#define FEAT 7
#define STATE 16
#define NB_SCAN 1954  // ceil(N_NODES/256)

// ---------------- zero an int buffer ----------------------------------------
__global__ __launch_bounds__(256) void k_zero(int* __restrict__ p, int n) {
    int i = blockIdx.x * 256 + threadIdx.x;
    if (i < n) p[i] = 0;
}

// ---------------- input layer: state = relu(x @ in_W + in_b) ----------------
__global__ __launch_bounds__(256) void k_input(const float* __restrict__ x,
                                               const float* __restrict__ W,
                                               const float* __restrict__ b,
                                               float* __restrict__ state) {
    int i = blockIdx.x * 256 + threadIdx.x;
    if (i >= N_NODES) return;
    float xi[FEAT];
#pragma unroll
    for (int f = 0; f < FEAT; ++f) xi[f] = x[(size_t)i * FEAT + f];
    float o[STATE];
#pragma unroll
    for (int s = 0; s < STATE; ++s) {
        float acc = b[s];
#pragma unroll
        for (int f = 0; f < FEAT; ++f) acc = fmaf(xi[f], W[f * STATE + s], acc);
        o[s] = fmaxf(acc, 0.f);
    }
    float4* dst = reinterpret_cast<float4*>(state + (size_t)i * STATE);
#pragma unroll
    for (int q = 0; q < 4; ++q)
        dst[q] = make_float4(o[4 * q], o[4 * q + 1], o[4 * q + 2], o[4 * q + 3]);
}

// ---------------- CSR build: histogram with position capture ----------------
__global__ __launch_bounds__(256) void k_hist(const int* __restrict__ ei,
                                              int* __restrict__ deg,
                                              int* __restrict__ pos) {
    int e = blockIdx.x * 256 + threadIdx.x;
    if (e >= N_EDGES) return;
    int d = ei[N_EDGES + e];
    pos[e] = atomicAdd(&deg[d], 1);
}

// ---------------- 3-kernel exclusive scan over deg[] ------------------------
__global__ __launch_bounds__(256) void k_scan1(const int* __restrict__ deg,
                                               int* __restrict__ offs,
                                               int* __restrict__ bsum) {
    __shared__ int wsum[4];
    int b = blockIdx.x, t = threadIdx.x, lane = t & 63, w = t >> 6;
    int i = b * 256 + t;
    int v = (i < N_NODES) ? deg[i] : 0;
    int s = v;
#pragma unroll
    for (int off = 1; off < 64; off <<= 1) {
        int o = __shfl_up(s, off);
        if (lane >= off) s += o;
    }
    if (lane == 63) wsum[w] = s;
    __syncthreads();
    int wofs = 0;
#pragma unroll
    for (int k = 0; k < 4; ++k)
        if (k < w) wofs += wsum[k];
    if (i < N_NODES) offs[i] = wofs + s - v;  // block-local exclusive
    if (t == 255) bsum[b] = wofs + s;         // block total
}

__global__ __launch_bounds__(256) void k_scan2(int* __restrict__ bsum) {
    __shared__ int wsum[4];
    __shared__ int carry_s;
    int t = threadIdx.x, lane = t & 63, w = t >> 6;
    if (t == 0) carry_s = 0;
    __syncthreads();
    for (int base = 0; base < NB_SCAN; base += 256) {
        int i = base + t;
        int v = (i < NB_SCAN) ? bsum[i] : 0;
        int s = v;
#pragma unroll
        for (int off = 1; off < 64; off <<= 1) {
            int o = __shfl_up(s, off);
            if (lane >= off) s += o;
        }
        if (lane == 63) wsum[w] = s;
        __syncthreads();
        int wofs = 0;
#pragma unroll
        for (int k = 0; k < 4; ++k)
            if (k < w) wofs += wsum[k];
        int incl = wofs + s;
        int carry = carry_s;
        if (i < NB_SCAN) bsum[i] = carry + incl - v;  // exclusive across chunks
        __syncthreads();
        if (t == 255) carry_s = carry + incl;
        __syncthreads();
    }
}

__global__ __launch_bounds__(256) void k_scan3(int* __restrict__ offs,
                                               const int* __restrict__ bsum) {
    int i = blockIdx.x * 256 + threadIdx.x;
    if (i < N_NODES) offs[i] += bsum[blockIdx.x];
}

// ---------------- scatter edge srcs into CSR slots --------------------------
__global__ __launch_bounds__(256) void k_scatter(const int* __restrict__ ei,
                                                 const int* __restrict__ offs,
                                                 const int* __restrict__ pos,
                                                 int* __restrict__ srcs) {
    int e = blockIdx.x * 256 + threadIdx.x;
    if (e >= N_EDGES) return;
    int d = ei[N_EDGES + e];
    srcs[offs[d] + pos[e]] = ei[e];
}

// ------- message = relu(state @ W + b) --------------------------------------
__global__ __launch_bounds__(256) void k_message(const float* __restrict__ state,
                                                 const float* __restrict__ W,
                                                 const float* __restrict__ b,
                                                 float* __restrict__ message) {
    int i = blockIdx.x * 256 + threadIdx.x;
    if (i >= N_NODES) return;
    const float4* sp = reinterpret_cast<const float4*>(state + (size_t)i * STATE);
    float4 v0 = sp[0], v1 = sp[1], v2 = sp[2], v3 = sp[3];
    float st[STATE] = {v0.x, v0.y, v0.z, v0.w, v1.x, v1.y, v1.z, v1.w,
                       v2.x, v2.y, v2.z, v2.w, v3.x, v3.y, v3.z, v3.w};
    float o[STATE];
#pragma unroll
    for (int s = 0; s < STATE; ++s) {
        float acc = b[s];
#pragma unroll
        for (int k = 0; k < STATE; ++k) acc = fmaf(st[k], W[k * STATE + s], acc);
        o[s] = fmaxf(acc, 0.f);
    }
    float4* mp = reinterpret_cast<float4*>(message + (size_t)i * STATE);
#pragma unroll
    for (int q = 0; q < 4; ++q)
        mp[q] = make_float4(o[4 * q], o[4 * q + 1], o[4 * q + 2], o[4 * q + 3]);
}

// ------- atomic-free gather + fused update: state += relu(sum @ W + b) ------
__global__ __launch_bounds__(256) void k_gather_update(
    const float* __restrict__ message, const int* __restrict__ offs,
    const int* __restrict__ deg, const int* __restrict__ srcs,
    const float* __restrict__ W, const float* __restrict__ b,
    float* __restrict__ state) {
    int i = blockIdx.x * 256 + threadIdx.x;
    if (i >= N_NODES) return;
    float acc[STATE];
#pragma unroll
    for (int s = 0; s < STATE; ++s) acc[s] = 0.f;
    int start = offs[i], n = deg[i];
    for (int j = 0; j < n; ++j) {
        int s = srcs[start + j];
        const float4* mp = reinterpret_cast<const float4*>(message + (size_t)s * STATE);
        float4 m0 = mp[0], m1 = mp[1], m2 = mp[2], m3 = mp[3];
        acc[0] += m0.x;  acc[1] += m0.y;  acc[2] += m0.z;  acc[3] += m0.w;
        acc[4] += m1.x;  acc[5] += m1.y;  acc[6] += m1.z;  acc[7] += m1.w;
        acc[8] += m2.x;  acc[9] += m2.y;  acc[10] += m2.z; acc[11] += m2.w;
        acc[12] += m3.x; acc[13] += m3.y; acc[14] += m3.z; acc[15] += m3.w;
    }
    float* sp = state + (size_t)i * STATE;
    float4* spv = reinterpret_cast<float4*>(sp);
    float4 s0 = spv[0], s1 = spv[1], s2 = spv[2], s3 = spv[3];
    float st[STATE] = {s0.x, s0.y, s0.z, s0.w, s1.x, s1.y, s1.z, s1.w,
                       s2.x, s2.y, s2.z, s2.w, s3.x, s3.y, s3.z, s3.w};
#pragma unroll
    for (int s = 0; s < STATE; ++s) {
        float a = b[s];
#pragma unroll
        for (int k = 0; k < STATE; ++k) a = fmaf(acc[k], W[k * STATE + s], a);
        st[s] += fmaxf(a, 0.f);
    }
#pragma unroll
    for (int q = 0; q < 4; ++q)
        spv[q] = make_float4(st[4 * q], st[4 * q + 1], st[4 * q + 2], st[4 * q + 3]);
}

// ------------- out[g] = out_b -----------------------------------------------
__global__ __launch_bounds__(256) void k_out_init(const float* __restrict__ out_b,
                                                  float* __restrict__ out) {
    int g = blockIdx.x * 256 + threadIdx.x;
    if (g < N_GRAPHS) out[g] = out_b[0];
}

// ------------- out[batch[i]] += dot(state[i], out_W) ------------------------
// batch is sorted -> wave-segmented reduction, ~1-2 atomics per wave.
__global__ __launch_bounds__(256) void k_reduce(const float* __restrict__ state,
                                                const int* __restrict__ batch,
                                                const float* __restrict__ out_W,
                                                float* __restrict__ out) {
    int i = blockIdx.x * 256 + threadIdx.x;
    int lane = threadIdx.x & 63;
    bool valid = (i < N_NODES);
    float v = 0.f;
    int bg = -1;
    if (valid) {
        bg = batch[i];
        const float4* sp = reinterpret_cast<const float4*>(state + (size_t)i * STATE);
        float4 s0 = sp[0], s1 = sp[1], s2 = sp[2], s3 = sp[3];
        float st[STATE] = {s0.x, s0.y, s0.z, s0.w, s1.x, s1.y, s1.z, s1.w,
                           s2.x, s2.y, s2.z, s2.w, s3.x, s3.y, s3.z, s3.w};
        float acc = 0.f;
#pragma unroll
        for (int k = 0; k < STATE; ++k) acc = fmaf(st[k], out_W[k], acc);
        v = acc;
    }
#pragma unroll
    for (int off = 1; off < 64; off <<= 1) {
        float ov = __shfl_up(v, off);
        int ob = __shfl_up(bg, off);
        if (lane >= off && ob == bg) v += ov;
    }
    int nb = __shfl_down(bg, 1);
    if (valid && (lane == 63 || nb != bg)) unsafeAtomicAdd(&out[bg], v);
}

extern "C" void kernel_launch(void* const* d_in, const int* in_sizes, int n_in,
                              void* d_out, int out_size, void* d_ws, size_t ws_size,
                              hipStream_t stream) {
    const float* x     = (const float*)d_in[0];
    const int*   ei    = (const int*)d_in[1];
    const int*   batch = (const int*)d_in[2];
    const float* in_W  = (const float*)d_in[3];
    const float* in_b  = (const float*)d_in[4];
    const float* msg_W = (const float*)d_in[5];
    const float* msg_b = (const float*)d_in[6];
    const float* upd_W = (const float*)d_in[7];
    const float* upd_b = (const float*)d_in[8];
    const float* out_W = (const float*)d_in[9];
    const float* out_b = (const float*)d_in[10];
    float* out = (float*)d_out;

    // workspace layout (~88 MB):
    float* state   = (float*)d_ws;                          // 32 MB
    float* message = state + (size_t)N_NODES * STATE;       // 32 MB
    int*   srcs    = (int*)(message + (size_t)N_NODES * STATE);  // 20 MB
    int*   deg     = srcs + N_EDGES;                        // 2 MB
    int*   offs    = deg + N_NODES;                         // 2 MB
    int*   bsum    = offs + N_NODES + 1;                    // 8 KB
    int*   pos     = (int*)message;  // overlap: pos only live during CSR build

    const int nbN = (N_NODES + 255) / 256;
    const int nbE = (N_EDGES + 255) / 256;
    const int nbG = (N_GRAPHS + 255) / 256;

    // ---- CSR build (by dst) ----
    k_zero<<<nbN, 256, 0, stream>>>(deg, N_NODES);
    k_hist<<<nbE, 256, 0, stream>>>(ei, deg, pos);
    k_scan1<<<NB_SCAN, 256, 0, stream>>>(deg, offs, bsum);
    k_scan2<<<1, 256, 0, stream>>>(bsum);
    k_scan3<<<NB_SCAN, 256, 0, stream>>>(offs, bsum);
    k_scatter<<<nbE, 256, 0, stream>>>(ei, offs, pos, srcs);

    // ---- GNN ----
    k_input<<<nbN, 256, 0, stream>>>(x, in_W, in_b, state);
    for (int r = 0; r < 4; ++r) {
        k_message<<<nbN, 256, 0, stream>>>(state, msg_W + r * STATE * STATE,
                                           msg_b + r * STATE, message);
        k_gather_update<<<nbN, 256, 0, stream>>>(message, offs, deg, srcs,
                                                 upd_W + r * STATE * STATE,
                                                 upd_b + r * STATE, state);
    }
    k_out_init<<<nbG, 256, 0, stream>>>(out_b, out);
    k_reduce<<<nbN, 256, 0, stream>>>(state, batch, out_W, out);
}